// Round 3
// baseline (190.735 us; speedup 1.0000x reference)
//
#include <hip/hip_runtime.h>

typedef float floatx4 __attribute__((ext_vector_type(4)));
typedef float floatx16 __attribute__((ext_vector_type(16)));
typedef __bf16 bf16x8 __attribute__((ext_vector_type(8)));
typedef __bf16 bf16x4 __attribute__((ext_vector_type(4)));
typedef __bf16 bf16x2 __attribute__((ext_vector_type(2)));
typedef float floatx2 __attribute__((ext_vector_type(2)));

#define MFMA16 __builtin_amdgcn_mfma_f32_16x16x32_bf16
#define MFMA32 __builtin_amdgcn_mfma_f32_32x32x16_bf16

typedef const __attribute__((address_space(1))) void* gas_t;
typedef __attribute__((address_space(3))) void* las_t;
#define GLD16(g, l) __builtin_amdgcn_global_load_lds((gas_t)(g), (las_t)(l), 16, 0, 0)

static __device__ __forceinline__ unsigned short f2bf(float f) {
  union { float f; unsigned int u; } v; v.f = f;
  unsigned int r = v.u + 0x7fffu + ((v.u >> 16) & 1u);
  return (unsigned short)(r >> 16);
}

// pack two f32 -> one dword of 2 bf16 (RNE; compiler emits v_cvt_pk_bf16_f32)
static __device__ __forceinline__ unsigned pk2(float a, float b) {
  floatx2 v; v[0] = a; v[1] = b;
  union { bf16x2 h; unsigned u; } u;
  u.h = __builtin_convertvector(v, bf16x2);
  return u.u;
}

// ---------------- fused prologue: cast x + transpose Wqkv + transpose Wproj -
static __device__ __forceinline__ void cast_transpose_tile(
    const float* __restrict__ in, unsigned short* __restrict__ out,
    int R, int C, int bx, int by) {
  const int r0 = by * 64, c0 = bx * 64;
  const int tid = threadIdx.x;
  __shared__ float tl[64][65];
  const int rr = tid >> 4, cc = (tid & 15) * 4;
#pragma unroll
  for (int i = 0; i < 4; ++i) {
    int row = rr + i * 16;
    float4 v = *(const float4*)(in + (size_t)(r0 + row) * C + c0 + cc);
    tl[row][cc] = v.x; tl[row][cc + 1] = v.y;
    tl[row][cc + 2] = v.z; tl[row][cc + 3] = v.w;
  }
  __syncthreads();
  const int cl = tid >> 2, rbase = (tid & 3) * 16;
  unsigned short o[16];
#pragma unroll
  for (int j = 0; j < 16; ++j) o[j] = f2bf(tl[rbase + j][cl]);
  unsigned short* dst = out + (size_t)(c0 + cl) * R + r0 + rbase;
  *(uint4*)dst = *(uint4*)o;
  *(uint4*)(dst + 8) = *(uint4*)(o + 8);
}

__global__ __launch_bounds__(256) void prologue_kernel(
    const float* __restrict__ x, unsigned short* __restrict__ Xb,
    const float* __restrict__ Wqkv, unsigned short* __restrict__ Wqkvt,
    const float* __restrict__ Wproj, unsigned short* __restrict__ Wprojt) {
  const int bid = blockIdx.x;
  if (bid < 4096) {
    int i = bid * 256 + threadIdx.x;
    float4 v = ((const float4*)x)[i];
    ushort4 o;
    o.x = f2bf(v.x); o.y = f2bf(v.y); o.z = f2bf(v.z); o.w = f2bf(v.w);
    ((ushort4*)Xb)[i] = o;
  } else if (bid < 4096 + 768) {
    int b2 = bid - 4096;
    cast_transpose_tile(Wqkv, Wqkvt, 1024, 3072, b2 % 48, b2 / 48);
  } else {
    int b3 = bid - 4096 - 768;
    cast_transpose_tile(Wproj, Wprojt, 1024, 1024, b3 % 16, b3 / 16);
  }
}

// ---------------- GEMM1: QKV = Xb @ WqkvT^T + bqkv, scatter -----------------
// Q[bh][t][d] (0.5*log2e folded), Kc[bh][t][d], Vt[bh][d][t].
// Epilogue bounces 64x64 wave-tiles through LDS (stride 72 = 144B, 16B-aligned
// rows) -> coalesced b128 stores. NOTE: t within batch = m0 & 2047 (batch is
// already encoded in bh) — raw m0 here was the round-8/9 corruption bug.
__global__ __launch_bounds__(256) void gemm_qkv(
    const unsigned short* __restrict__ A,
    const unsigned short* __restrict__ Bt,
    const float* __restrict__ bias,
    unsigned short* __restrict__ Q,
    unsigned short* __restrict__ Kc,
    unsigned short* __restrict__ Vt) {
  const int K = 1024;
  const int m0 = blockIdx.y * 128, n0 = blockIdx.x * 128;
  const int tid = threadIdx.x, w = tid >> 6, l = tid & 63;
  const int l16 = l & 15, lq = l >> 4;
  const int wm = w >> 1, wn = w & 1;
  const int which = n0 >> 10;

  __shared__ __align__(16) unsigned short SH[16384];
  unsigned short* As = SH;          // 128*64
  unsigned short* Bs = SH + 8192;   // 128*64

  floatx4 acc[4][4] = {};

  int sA[4], sB[4];
  unsigned ldso[4];
#pragma unroll
  for (int j = 0; j < 4; ++j) {
    int s = j * 256 + tid;
    int row = s >> 3, blk = (s & 7) ^ (row & 7);
    sA[j] = (m0 + row) * K + blk * 8;
    sB[j] = (n0 + row) * K + blk * 8;
    ldso[j] = (unsigned)(j * 256 + w * 64) * 8;
  }

  if (which == 2) {
    for (int k0 = 0; k0 < K; k0 += 64) {
      __syncthreads();
#pragma unroll
      for (int j = 0; j < 4; ++j) {
        GLD16(A + sA[j] + k0, As + ldso[j]);
        GLD16(Bt + sB[j] + k0, Bs + ldso[j]);
      }
      __syncthreads();
#pragma unroll
      for (int kk = 0; kk < 2; ++kk) {
        bf16x8 af[4], bf[4];
#pragma unroll
        for (int mi = 0; mi < 4; ++mi) {
          int row = wm * 64 + mi * 16 + l16;
          int blk = (kk * 4 + lq) ^ (l16 & 7);
          af[mi] = *(const bf16x8*)(As + row * 64 + blk * 8);
        }
#pragma unroll
        for (int ni = 0; ni < 4; ++ni) {
          int row = wn * 64 + ni * 16 + l16;
          int blk = (kk * 4 + lq) ^ (l16 & 7);
          bf[ni] = *(const bf16x8*)(Bs + row * 64 + blk * 8);
        }
#pragma unroll
        for (int ni = 0; ni < 4; ++ni)
#pragma unroll
          for (int mi = 0; mi < 4; ++mi)
            acc[mi][ni] = MFMA16(af[mi], bf[ni], acc[mi][ni], 0, 0, 0);
      }
    }
    // V: D[t(packed)][col]; bounce to [d][t] LDS, coalesced 128B-segment store
    float bv[4];
#pragma unroll
    for (int ni = 0; ni < 4; ++ni) bv[ni] = bias[n0 + wn * 64 + ni * 16 + l16];
    __syncthreads();
    unsigned short* E = SH + w * 2304;  // 32 rows x stride 72 (144B, 16B-mult)
    const int bh = (m0 >> 11) * 16 + ((n0 & 1023) >> 6) + wn;
    const int tt0 = (m0 & 2047) + wm * 64;
#pragma unroll
    for (int p = 0; p < 2; ++p) {
#pragma unroll
      for (int n2 = 0; n2 < 2; ++n2) {
        int ni = p * 2 + n2;
#pragma unroll
        for (int mi = 0; mi < 4; ++mi) {
          floatx4 vv = acc[mi][ni] + bv[ni];
          *(bf16x4*)(E + (n2 * 16 + l16) * 72 + mi * 16 + lq * 4) =
              __builtin_convertvector(vv, bf16x4);
        }
      }
#pragma unroll
      for (int s = 0; s < 4; ++s) {
        int dl = s * 8 + (l >> 3);
        bf16x8 vv = *(const bf16x8*)(E + dl * 72 + (l & 7) * 8);
        *(bf16x8*)(Vt + ((size_t)bh * 64 + p * 32 + dl) * 2048 + tt0 +
                   (l & 7) * 8) = vv;
      }
    }
  } else {
    for (int k0 = 0; k0 < K; k0 += 64) {
      __syncthreads();
#pragma unroll
      for (int j = 0; j < 4; ++j) {
        GLD16(A + sA[j] + k0, As + ldso[j]);
        GLD16(Bt + sB[j] + k0, Bs + ldso[j]);
      }
      __syncthreads();
#pragma unroll
      for (int kk = 0; kk < 2; ++kk) {
        bf16x8 af[4], bf[4];
#pragma unroll
        for (int mi = 0; mi < 4; ++mi) {
          int row = wm * 64 + mi * 16 + l16;
          int blk = (kk * 4 + lq) ^ (l16 & 7);
          af[mi] = *(const bf16x8*)(As + row * 64 + blk * 8);
        }
#pragma unroll
        for (int ni = 0; ni < 4; ++ni) {
          int row = wn * 64 + ni * 16 + l16;
          int blk = (kk * 4 + lq) ^ (l16 & 7);
          bf[ni] = *(const bf16x8*)(Bs + row * 64 + blk * 8);
        }
#pragma unroll
        for (int ni = 0; ni < 4; ++ni)
#pragma unroll
          for (int mi = 0; mi < 4; ++mi)
            acc[mi][ni] = MFMA16(bf[ni], af[mi], acc[mi][ni], 0, 0, 0);
      }
    }
    // Q/K: D[col(packed d)][t]; bounce to [t][d] LDS, coalesced 1KB stores
    const float sc = (which == 0) ? 0.7213475204444817f : 1.0f;
    unsigned short* dst = (which == 0) ? Q : Kc;
    __syncthreads();
    unsigned short* E = SH + w * 2304;
    const int bh = (m0 >> 11) * 16 + ((n0 & 1023) >> 6) + wn;
    const size_t gbase = ((size_t)bh * 2048 + (m0 & 2047) + wm * 64) * 64;
#pragma unroll
    for (int p = 0; p < 2; ++p) {
#pragma unroll
      for (int m2 = 0; m2 < 2; ++m2) {
        int mi = p * 2 + m2;
#pragma unroll
        for (int ni = 0; ni < 4; ++ni) {
          int col0 = n0 + wn * 64 + ni * 16 + lq * 4;
          floatx4 bv = *(const floatx4*)(bias + col0);
          floatx4 vv = (acc[mi][ni] + bv) * sc;
          *(bf16x4*)(E + (m2 * 16 + l16) * 72 + ni * 16 + lq * 4) =
              __builtin_convertvector(vv, bf16x4);
        }
      }
#pragma unroll
      for (int s = 0; s < 4; ++s) {
        int rl = s * 8 + (l >> 3);
        bf16x8 vv = *(const bf16x8*)(E + rl * 72 + (l & 7) * 8);
        *(bf16x8*)(dst + gbase + (size_t)(p * 32 + rl) * 64 + (l & 7) * 8) =
            vv;
      }
    }
  }
}

// ---------------- attention: 32x32 MFMA, reg-resident P, no k-split --------
// 4 waves x 32 q-rows, full T sweep, K/V chunk (64 k) double-buffered in LDS.
// S^T C-frag (32x32): lane = col q (l&31), rows k = (r&3)+8(r>>2)+4(l>>5).
// PV B-frag (k16 step s): same q col, k = 16s+8(l>>5)+j -> built from S^T
// regs with shfl_xor(32) + per-half select (defensive, provably correct).
__global__ __launch_bounds__(256, 2) void attn_kernel(
    const unsigned short* __restrict__ Q,
    const unsigned short* __restrict__ Kc,
    const unsigned short* __restrict__ Vt,
    unsigned short* __restrict__ AO) {
  const int T = 2048;
  const int bh = blockIdx.y, q0 = blockIdx.x * 128;
  const int tid = threadIdx.x, w = tid >> 6, l = tid & 63;
  const int r31 = l & 31, g = l >> 5;

  __shared__ __align__(16) unsigned short KVs[2][2][4096];  // 32 KB

  // Q B-frags (scale+log2e pre-folded): col q = r31, k(d) = 16*ds + g*8 + j
  bf16x8 qf[4];
  {
    const unsigned short* qr =
        Q + ((size_t)bh * T + q0 + w * 32 + r31) * 64 + g * 8;
#pragma unroll
    for (int ds = 0; ds < 4; ++ds) qf[ds] = *(const bf16x8*)(qr + ds * 16);
  }

  floatx16 o_acc[2] = {};
  float l_lane = 0.f;

  const unsigned short* kbase = Kc + (size_t)bh * T * 64;
  const unsigned short* vbase = Vt + (size_t)bh * 64 * T;
  int kro[2], vro[2];
  unsigned ldso[2];
#pragma unroll
  for (int j = 0; j < 2; ++j) {
    int s = j * 256 + tid;
    int row = s >> 3, blk = (s & 7) ^ (row & 7);
    kro[j] = row * 64 + blk * 8;  // + chunk*4096
    vro[j] = row * T + blk * 8;   // + chunk*64
    ldso[j] = (unsigned)(j * 256 + (tid & 192)) * 8;  // wave-uniform base!
  }

#pragma unroll
  for (int j = 0; j < 2; ++j) {
    GLD16(kbase + kro[j], &KVs[0][0][ldso[j]]);
    GLD16(vbase + vro[j], &KVs[0][1][ldso[j]]);
  }

  for (int c = 0; c < 32; ++c) {
    __syncthreads();
    if (c < 31) {
      const int nb = (c + 1) & 1;
#pragma unroll
      for (int j = 0; j < 2; ++j) {
        GLD16(kbase + (c + 1) * 4096 + kro[j], &KVs[nb][0][ldso[j]]);
        GLD16(vbase + (c + 1) * 64 + vro[j], &KVs[nb][1][ldso[j]]);
      }
    }
    const unsigned short* kb = KVs[c & 1][0];
    const unsigned short* vb = KVs[c & 1][1];

    // QK^T: two 32k x 32q tiles
    floatx16 sac[2];
#pragma unroll
    for (int kt = 0; kt < 2; ++kt) {
      const int row = kt * 32 + r31, rx = row & 7;
      const unsigned short* kr = kb + row * 64;
      floatx16 z = {};
#pragma unroll
      for (int ds = 0; ds < 4; ++ds)
        z = MFMA32(*(const bf16x8*)(kr + ((ds * 2 + g) ^ rx) * 8), qf[ds], z,
                   0, 0, 0);
      sac[kt] = z;
    }

    // exp2 -> P B-frags in registers; lane-32 exchange via shfl_xor + select
    bf16x8 pf[4];
#pragma unroll
    for (int kt = 0; kt < 2; ++kt) {
      float p[16];
#pragma unroll
      for (int r = 0; r < 16; ++r) p[r] = __builtin_amdgcn_exp2f(sac[kt][r]);
      l_lane += (((p[0] + p[1]) + (p[2] + p[3])) +
                 ((p[4] + p[5]) + (p[6] + p[7]))) +
                (((p[8] + p[9]) + (p[10] + p[11])) +
                 ((p[12] + p[13]) + (p[14] + p[15])));
#pragma unroll
      for (int s2 = 0; s2 < 2; ++s2) {
        unsigned cA = pk2(p[8 * s2 + 0], p[8 * s2 + 1]);  // rows 16s2+{0,1}+4g
        unsigned cB = pk2(p[8 * s2 + 2], p[8 * s2 + 3]);  // rows 16s2+{2,3}+4g
        unsigned cC = pk2(p[8 * s2 + 4], p[8 * s2 + 5]);  // rows 16s2+{8,9}+4g
        unsigned cD = pk2(p[8 * s2 + 6], p[8 * s2 + 7]);  // rows 16s2+{10,11}+4g
        unsigned xA = (unsigned)__shfl_xor((int)cA, 32, 64);
        unsigned xB = (unsigned)__shfl_xor((int)cB, 32, 64);
        unsigned xC = (unsigned)__shfl_xor((int)cC, 32, 64);
        unsigned xD = (unsigned)__shfl_xor((int)cD, 32, 64);
        union { unsigned u[4]; bf16x8 v; } pu;
        pu.u[0] = g ? xC : cA;  // dw0 = {cA_lo, cC_lo}
        pu.u[1] = g ? xD : cB;  // dw1 = {cB_lo, cD_lo}
        pu.u[2] = g ? cC : xA;  // dw2 = {cA_hi, cC_hi}
        pu.u[3] = g ? cD : xB;  // dw3 = {cB_hi, cD_hi}
        pf[kt * 2 + s2] = pu.v;
      }
    }

    // O^T += V^T * P^T : 2 dt x 4 k16 steps
#pragma unroll
    for (int dt = 0; dt < 2; ++dt) {
      const int row = dt * 32 + r31, rx = row & 7;
      const unsigned short* vr = vb + row * 64;
#pragma unroll
      for (int s = 0; s < 4; ++s) {
        bf16x8 vf = *(const bf16x8*)(vr + ((s * 2 + g) ^ rx) * 8);
        o_acc[dt] = MFMA32(vf, pf[s], o_acc[dt], 0, 0, 0);
      }
    }
  }

  // epilogue: lane-local denom (one q per lane), partner holds other k-half
  float ls = l_lane + __shfl_xor(l_lane, 32, 64);
  float inv = 1.0f / ls;
  const int b = bh >> 4, h = bh & 15;
  const int t = q0 + w * 32 + r31;
  unsigned short* ao = AO + ((size_t)b * 2048 + t) * 1024 + h * 64;
#pragma unroll
  for (int dt = 0; dt < 2; ++dt)
#pragma unroll
    for (int rq = 0; rq < 4; ++rq) {
      floatx4 ov;
      ov[0] = o_acc[dt][rq * 4 + 0]; ov[1] = o_acc[dt][rq * 4 + 1];
      ov[2] = o_acc[dt][rq * 4 + 2]; ov[3] = o_acc[dt][rq * 4 + 3];
      ov *= inv;
      *(bf16x4*)(ao + dt * 32 + rq * 8 + g * 4) =
          __builtin_convertvector(ov, bf16x4);
    }
}

// ---------------- GEMM2: out = AO @ WprojT^T + bproj, swapped -> float4 -----
__global__ __launch_bounds__(256) void gemm_proj(
    const unsigned short* __restrict__ A,
    const unsigned short* __restrict__ Bt,
    const float* __restrict__ bias,
    float* __restrict__ out) {
  const int K = 1024, N = 1024;
  const int m0 = blockIdx.y * 128, n0 = blockIdx.x * 64;
  const int tid = threadIdx.x, w = tid >> 6, l = tid & 63;
  const int l16 = l & 15, lq = l >> 4;

  __shared__ __align__(16) unsigned short As[128 * 64];
  __shared__ __align__(16) unsigned short Bs[64 * 64];

  floatx4 acc[2][4] = {};

  int sA[4], sB[2];
  unsigned ldsoA[4], ldsoB[2];
#pragma unroll
  for (int j = 0; j < 4; ++j) {
    int s = j * 256 + tid;
    int row = s >> 3, blk = (s & 7) ^ (row & 7);
    sA[j] = (m0 + row) * K + blk * 8;
    ldsoA[j] = (unsigned)(j * 256 + w * 64) * 8;
  }
#pragma unroll
  for (int j = 0; j < 2; ++j) {
    int s = j * 256 + tid;
    int row = s >> 3, blk = (s & 7) ^ (row & 7);
    sB[j] = (n0 + row) * K + blk * 8;
    ldsoB[j] = (unsigned)(j * 256 + w * 64) * 8;
  }

  for (int k0 = 0; k0 < K; k0 += 64) {
    __syncthreads();
#pragma unroll
    for (int j = 0; j < 4; ++j) GLD16(A + sA[j] + k0, As + ldsoA[j]);
#pragma unroll
    for (int j = 0; j < 2; ++j) GLD16(Bt + sB[j] + k0, Bs + ldsoB[j]);
    __syncthreads();
#pragma unroll
    for (int kk = 0; kk < 2; ++kk) {
      bf16x8 af[2], bf[4];
#pragma unroll
      for (int mi = 0; mi < 2; ++mi) {
        int row = w * 32 + mi * 16 + l16;
        int blk = (kk * 4 + lq) ^ (l16 & 7);
        af[mi] = *(const bf16x8*)(As + row * 64 + blk * 8);
      }
#pragma unroll
      for (int ni = 0; ni < 4; ++ni) {
        int row = ni * 16 + l16;
        int blk = (kk * 4 + lq) ^ (l16 & 7);
        bf[ni] = *(const bf16x8*)(Bs + row * 64 + blk * 8);
      }
#pragma unroll
      for (int ni = 0; ni < 4; ++ni)
#pragma unroll
        for (int mi = 0; mi < 2; ++mi)
          acc[mi][ni] = MFMA16(bf[ni], af[mi], acc[mi][ni], 0, 0, 0);
    }
  }

#pragma unroll
  for (int mi = 0; mi < 2; ++mi) {
    int t = m0 + w * 32 + mi * 16 + l16;
#pragma unroll
    for (int ni = 0; ni < 4; ++ni) {
      int col0 = n0 + ni * 16 + lq * 4;
      floatx4 bv = *(const floatx4*)(bias + col0);
      *(floatx4*)(out + (size_t)t * N + col0) = acc[mi][ni] + bv;
    }
  }
}

extern "C" void kernel_launch(void* const* d_in, const int* in_sizes, int n_in,
                              void* d_out, int out_size, void* d_ws,
                              size_t ws_size, hipStream_t stream) {
  const float* x     = (const float*)d_in[0];
  const float* Wqkv  = (const float*)d_in[1];
  const float* bqkv  = (const float*)d_in[2];
  const float* Wproj = (const float*)d_in[3];
  const float* bproj = (const float*)d_in[4];
  float* out = (float*)d_out;

  unsigned short* Xb     = (unsigned short*)d_ws;  // 4096x1024
  unsigned short* Wqkvt  = Xb + 4194304;           // 3072x1024 (transposed)
  unsigned short* Wprojt = Wqkvt + 3145728;        // 1024x1024 (transposed)
  unsigned short* Qb     = Wprojt + 1048576;       // 32x2048x64 (pre-scaled)
  unsigned short* Kb     = Qb + 4194304;           // 32x2048x64
  unsigned short* Vtb    = Kb + 4194304;           // 32x64x2048
  unsigned short* AOb    = Vtb + 4194304;          // 4096x1024

  prologue_kernel<<<5120, 256, 0, stream>>>(x, Xb, Wqkv, Wqkvt, Wproj, Wprojt);
  gemm_qkv<<<dim3(24, 32), 256, 0, stream>>>(Xb, Wqkvt, bqkv, Qb, Kb, Vtb);
  attn_kernel<<<dim3(16, 32), 256, 0, stream>>>(Qb, Kb, Vtb, AOb);
  gemm_proj<<<dim3(16, 32), 256, 0, stream>>>(AOb, Wprojt, bproj, out);
}

// Round 4
// 184.470 us; speedup vs baseline: 1.0340x; 1.0340x over previous
//
#include <hip/hip_runtime.h>

typedef float floatx4 __attribute__((ext_vector_type(4)));
typedef float floatx16 __attribute__((ext_vector_type(16)));
typedef __bf16 bf16x8 __attribute__((ext_vector_type(8)));
typedef __bf16 bf16x4 __attribute__((ext_vector_type(4)));
typedef __bf16 bf16x2 __attribute__((ext_vector_type(2)));
typedef float floatx2 __attribute__((ext_vector_type(2)));

#define MFMA16 __builtin_amdgcn_mfma_f32_16x16x32_bf16
#define MFMA32 __builtin_amdgcn_mfma_f32_32x32x16_bf16

typedef const __attribute__((address_space(1))) void* gas_t;
typedef __attribute__((address_space(3))) void* las_t;
#define GLD16(g, l) __builtin_amdgcn_global_load_lds((gas_t)(g), (las_t)(l), 16, 0, 0)

static __device__ __forceinline__ unsigned short f2bf(float f) {
  union { float f; unsigned int u; } v; v.f = f;
  unsigned int r = v.u + 0x7fffu + ((v.u >> 16) & 1u);
  return (unsigned short)(r >> 16);
}

// pack two f32 -> one dword of 2 bf16 (RNE; compiler emits v_cvt_pk_bf16_f32)
static __device__ __forceinline__ unsigned pk2(float a, float b) {
  floatx2 v; v[0] = a; v[1] = b;
  union { bf16x2 h; unsigned u; } u;
  u.h = __builtin_convertvector(v, bf16x2);
  return u.u;
}

// ---------------- fused prologue: cast x + transpose Wqkv + transpose Wproj -
static __device__ __forceinline__ void cast_transpose_tile(
    const float* __restrict__ in, unsigned short* __restrict__ out,
    int R, int C, int bx, int by) {
  const int r0 = by * 64, c0 = bx * 64;
  const int tid = threadIdx.x;
  __shared__ float tl[64][65];
  const int rr = tid >> 4, cc = (tid & 15) * 4;
#pragma unroll
  for (int i = 0; i < 4; ++i) {
    int row = rr + i * 16;
    float4 v = *(const float4*)(in + (size_t)(r0 + row) * C + c0 + cc);
    tl[row][cc] = v.x; tl[row][cc + 1] = v.y;
    tl[row][cc + 2] = v.z; tl[row][cc + 3] = v.w;
  }
  __syncthreads();
  const int cl = tid >> 2, rbase = (tid & 3) * 16;
  unsigned short o[16];
#pragma unroll
  for (int j = 0; j < 16; ++j) o[j] = f2bf(tl[rbase + j][cl]);
  unsigned short* dst = out + (size_t)(c0 + cl) * R + r0 + rbase;
  *(uint4*)dst = *(uint4*)o;
  *(uint4*)(dst + 8) = *(uint4*)(o + 8);
}

__global__ __launch_bounds__(256) void prologue_kernel(
    const float* __restrict__ x, unsigned short* __restrict__ Xb,
    const float* __restrict__ Wqkv, unsigned short* __restrict__ Wqkvt,
    const float* __restrict__ Wproj, unsigned short* __restrict__ Wprojt) {
  const int bid = blockIdx.x;
  if (bid < 4096) {
    int i = bid * 256 + threadIdx.x;
    float4 v = ((const float4*)x)[i];
    ushort4 o;
    o.x = f2bf(v.x); o.y = f2bf(v.y); o.z = f2bf(v.z); o.w = f2bf(v.w);
    ((ushort4*)Xb)[i] = o;
  } else if (bid < 4096 + 768) {
    int b2 = bid - 4096;
    cast_transpose_tile(Wqkv, Wqkvt, 1024, 3072, b2 % 48, b2 / 48);
  } else {
    int b3 = bid - 4096 - 768;
    cast_transpose_tile(Wproj, Wprojt, 1024, 1024, b3 % 16, b3 / 16);
  }
}

// ---------------- GEMM1: QKV = Xb @ WqkvT^T + bqkv, scatter -----------------
// Q[bh][t][d] (0.5*log2e folded), Kc[bh][t][d], Vt[bh][d][t'].
// V's t-axis is stored PERMUTED by tau = within-16 involution
//   tau: {0-3}->{0-3}, {4-7}->{8-11}, {8-11}->{4-7}, {12-15}->{12-15}
// so attention's PV MFMA can consume P fragments in native S^T register
// order (positional pairing; see attn_kernel).
__global__ __launch_bounds__(256) void gemm_qkv(
    const unsigned short* __restrict__ A,
    const unsigned short* __restrict__ Bt,
    const float* __restrict__ bias,
    unsigned short* __restrict__ Q,
    unsigned short* __restrict__ Kc,
    unsigned short* __restrict__ Vt) {
  const int K = 1024;
  const int m0 = blockIdx.y * 128, n0 = blockIdx.x * 128;
  const int tid = threadIdx.x, w = tid >> 6, l = tid & 63;
  const int l16 = l & 15, lq = l >> 4;
  const int wm = w >> 1, wn = w & 1;
  const int which = n0 >> 10;

  __shared__ __align__(16) unsigned short SH[16384];
  unsigned short* As = SH;          // 128*64
  unsigned short* Bs = SH + 8192;   // 128*64

  floatx4 acc[4][4] = {};

  int sA[4], sB[4];
  unsigned ldso[4];
#pragma unroll
  for (int j = 0; j < 4; ++j) {
    int s = j * 256 + tid;
    int row = s >> 3, blk = (s & 7) ^ (row & 7);
    sA[j] = (m0 + row) * K + blk * 8;
    sB[j] = (n0 + row) * K + blk * 8;
    ldso[j] = (unsigned)(j * 256 + w * 64) * 8;
  }

  if (which == 2) {
    for (int k0 = 0; k0 < K; k0 += 64) {
      __syncthreads();
#pragma unroll
      for (int j = 0; j < 4; ++j) {
        GLD16(A + sA[j] + k0, As + ldso[j]);
        GLD16(Bt + sB[j] + k0, Bs + ldso[j]);
      }
      __syncthreads();
#pragma unroll
      for (int kk = 0; kk < 2; ++kk) {
        bf16x8 af[4], bf[4];
#pragma unroll
        for (int mi = 0; mi < 4; ++mi) {
          int row = wm * 64 + mi * 16 + l16;
          int blk = (kk * 4 + lq) ^ (l16 & 7);
          af[mi] = *(const bf16x8*)(As + row * 64 + blk * 8);
        }
#pragma unroll
        for (int ni = 0; ni < 4; ++ni) {
          int row = wn * 64 + ni * 16 + l16;
          int blk = (kk * 4 + lq) ^ (l16 & 7);
          bf[ni] = *(const bf16x8*)(Bs + row * 64 + blk * 8);
        }
#pragma unroll
        for (int ni = 0; ni < 4; ++ni)
#pragma unroll
          for (int mi = 0; mi < 4; ++mi)
            acc[mi][ni] = MFMA16(af[mi], bf[ni], acc[mi][ni], 0, 0, 0);
      }
    }
    // V: D[t(packed)][col]; bounce to [d][t] LDS; store with tau-permuted t.
    // Global position block 8m (m=l&7) holds t = {bc..bc+3, bc+8..bc+11},
    // bc = 16*(m>>1) + 4*(m&1)  ->  two b64 LDS reads, one b128 store.
    float bv[4];
#pragma unroll
    for (int ni = 0; ni < 4; ++ni) bv[ni] = bias[n0 + wn * 64 + ni * 16 + l16];
    __syncthreads();
    unsigned short* E = SH + w * 2304;  // 32 rows x stride 72 (144B, 16B-mult)
    const int bh = (m0 >> 11) * 16 + ((n0 & 1023) >> 6) + wn;
    const int tt0 = (m0 & 2047) + wm * 64;
    const int m8 = l & 7, bc = 16 * (m8 >> 1) + 4 * (m8 & 1);
#pragma unroll
    for (int p = 0; p < 2; ++p) {
#pragma unroll
      for (int n2 = 0; n2 < 2; ++n2) {
        int ni = p * 2 + n2;
#pragma unroll
        for (int mi = 0; mi < 4; ++mi) {
          floatx4 vv = acc[mi][ni] + bv[ni];
          *(bf16x4*)(E + (n2 * 16 + l16) * 72 + mi * 16 + lq * 4) =
              __builtin_convertvector(vv, bf16x4);
        }
      }
#pragma unroll
      for (int s = 0; s < 4; ++s) {
        int dl = s * 8 + (l >> 3);
        union { bf16x4 h[2]; bf16x8 v; } uu;
        uu.h[0] = *(const bf16x4*)(E + dl * 72 + bc);
        uu.h[1] = *(const bf16x4*)(E + dl * 72 + bc + 8);
        *(bf16x8*)(Vt + ((size_t)bh * 64 + p * 32 + dl) * 2048 + tt0 +
                   m8 * 8) = uu.v;
      }
    }
  } else {
    for (int k0 = 0; k0 < K; k0 += 64) {
      __syncthreads();
#pragma unroll
      for (int j = 0; j < 4; ++j) {
        GLD16(A + sA[j] + k0, As + ldso[j]);
        GLD16(Bt + sB[j] + k0, Bs + ldso[j]);
      }
      __syncthreads();
#pragma unroll
      for (int kk = 0; kk < 2; ++kk) {
        bf16x8 af[4], bf[4];
#pragma unroll
        for (int mi = 0; mi < 4; ++mi) {
          int row = wm * 64 + mi * 16 + l16;
          int blk = (kk * 4 + lq) ^ (l16 & 7);
          af[mi] = *(const bf16x8*)(As + row * 64 + blk * 8);
        }
#pragma unroll
        for (int ni = 0; ni < 4; ++ni) {
          int row = wn * 64 + ni * 16 + l16;
          int blk = (kk * 4 + lq) ^ (l16 & 7);
          bf[ni] = *(const bf16x8*)(Bs + row * 64 + blk * 8);
        }
#pragma unroll
        for (int ni = 0; ni < 4; ++ni)
#pragma unroll
          for (int mi = 0; mi < 4; ++mi)
            acc[mi][ni] = MFMA16(bf[ni], af[mi], acc[mi][ni], 0, 0, 0);
      }
    }
    // Q/K: D[col(packed d)][t]; bounce to [t][d] LDS, coalesced 1KB stores
    const float sc = (which == 0) ? 0.7213475204444817f : 1.0f;
    unsigned short* dst = (which == 0) ? Q : Kc;
    __syncthreads();
    unsigned short* E = SH + w * 2304;
    const int bh = (m0 >> 11) * 16 + ((n0 & 1023) >> 6) + wn;
    const size_t gbase = ((size_t)bh * 2048 + (m0 & 2047) + wm * 64) * 64;
#pragma unroll
    for (int p = 0; p < 2; ++p) {
#pragma unroll
      for (int m2 = 0; m2 < 2; ++m2) {
        int mi = p * 2 + m2;
#pragma unroll
        for (int ni = 0; ni < 4; ++ni) {
          int col0 = n0 + wn * 64 + ni * 16 + lq * 4;
          floatx4 bv = *(const floatx4*)(bias + col0);
          floatx4 vv = (acc[mi][ni] + bv) * sc;
          *(bf16x4*)(E + (m2 * 16 + l16) * 72 + ni * 16 + lq * 4) =
              __builtin_convertvector(vv, bf16x4);
        }
      }
#pragma unroll
      for (int s = 0; s < 4; ++s) {
        int rl = s * 8 + (l >> 3);
        bf16x8 vv = *(const bf16x8*)(E + rl * 72 + (l & 7) * 8);
        *(bf16x8*)(dst + gbase + (size_t)(p * 32 + rl) * 64 + (l & 7) * 8) =
            vv;
      }
    }
  }
}

// ---------------- attention: 32x32 MFMA, reg-resident P, 128k periods ------
// 4 waves x 32 q-rows, full T sweep. K/V staged in 128-k periods (2 chunks),
// double-buffered (64 KB LDS) -> GLDs get a full period (~2x compute) before
// the barrier that drains them; barriers halved to 16.
// S^T C-frag (32x32): lane = col q (l&31), rows k = (r&3)+8(r>>2)+4(l>>5).
// V's k-axis is tau-permuted in global memory (see gemm_qkv), so PV consumes
// P in NATIVE register order: pf dwords = pk2 of consecutive S regs. No
// cross-lane exchange at all.
__global__ __launch_bounds__(256, 2) void attn_kernel(
    const unsigned short* __restrict__ Q,
    const unsigned short* __restrict__ Kc,
    const unsigned short* __restrict__ Vt,
    unsigned short* __restrict__ AO) {
  const int T = 2048;
  const int bh = blockIdx.y, q0 = blockIdx.x * 128;
  const int tid = threadIdx.x, w = tid >> 6, l = tid & 63;
  const int r31 = l & 31, g = l >> 5;

  __shared__ __align__(16) unsigned short KVs[2][2][2][4096];  // 64 KB
  // [buf][K=0/V=1][chunk-in-period][64x64]

  // Q B-frags (scale+log2e pre-folded): col q = r31, k(d) = 16*ds + g*8 + j
  bf16x8 qf[4];
  {
    const unsigned short* qr =
        Q + ((size_t)bh * T + q0 + w * 32 + r31) * 64 + g * 8;
#pragma unroll
    for (int ds = 0; ds < 4; ++ds) qf[ds] = *(const bf16x8*)(qr + ds * 16);
  }

  floatx16 o_acc[2] = {};
  float l_lane = 0.f;

  const unsigned short* kbase = Kc + (size_t)bh * T * 64;
  const unsigned short* vbase = Vt + (size_t)bh * 64 * T;
  int kro[2], vro[2];
  unsigned ldso[2];
#pragma unroll
  for (int j = 0; j < 2; ++j) {
    int s = j * 256 + tid;
    int row = s >> 3, blk = (s & 7) ^ (row & 7);
    kro[j] = row * 64 + blk * 8;  // + chunk*4096
    vro[j] = row * T + blk * 8;   // + chunk*64
    ldso[j] = (unsigned)(j * 256 + (tid & 192)) * 8;  // wave-uniform base
  }

  // stage period pp (chunks 2pp, 2pp+1) into buffer nb
#define STAGE_PERIOD(pp, nb)                                              \
  {                                                                       \
    _Pragma("unroll") for (int c2 = 0; c2 < 2; ++c2) {                    \
      const int c = (pp) * 2 + c2;                                        \
      _Pragma("unroll") for (int j = 0; j < 2; ++j) {                     \
        GLD16(kbase + c * 4096 + kro[j], &KVs[nb][0][c2][ldso[j]]);       \
        GLD16(vbase + c * 64 + vro[j], &KVs[nb][1][c2][ldso[j]]);         \
      }                                                                   \
    }                                                                     \
  }

  STAGE_PERIOD(0, 0);

  for (int p = 0; p < 16; ++p) {
    __syncthreads();  // drains this wave's GLDs for period p (issued 1 ago)
    if (p < 15) {
      const int nb = (p + 1) & 1;
      STAGE_PERIOD(p + 1, nb);
    }
    const int pb = p & 1;
#pragma unroll
    for (int c2 = 0; c2 < 2; ++c2) {
      const unsigned short* kb = &KVs[pb][0][c2][0];
      const unsigned short* vb = &KVs[pb][1][c2][0];

      // QK^T: two 32k x 32q tiles
      bf16x8 pf[4];
#pragma unroll
      for (int kt = 0; kt < 2; ++kt) {
        const int row = kt * 32 + r31, rx = row & 7;
        const unsigned short* kr = kb + row * 64;
        floatx16 z = {};
#pragma unroll
        for (int ds = 0; ds < 4; ++ds)
          z = MFMA32(*(const bf16x8*)(kr + ((ds * 2 + g) ^ rx) * 8), qf[ds],
                     z, 0, 0, 0);

        float pe[16];
#pragma unroll
        for (int r = 0; r < 16; ++r) pe[r] = __builtin_amdgcn_exp2f(z[r]);
        l_lane += (((pe[0] + pe[1]) + (pe[2] + pe[3])) +
                   ((pe[4] + pe[5]) + (pe[6] + pe[7]))) +
                  (((pe[8] + pe[9]) + (pe[10] + pe[11])) +
                   ((pe[12] + pe[13]) + (pe[14] + pe[15])));
        // native-order P fragments (tau-permuted V absorbs the layout)
#pragma unroll
        for (int s2 = 0; s2 < 2; ++s2) {
          union { unsigned u[4]; bf16x8 v; } pu;
          pu.u[0] = pk2(pe[8 * s2 + 0], pe[8 * s2 + 1]);
          pu.u[1] = pk2(pe[8 * s2 + 2], pe[8 * s2 + 3]);
          pu.u[2] = pk2(pe[8 * s2 + 4], pe[8 * s2 + 5]);
          pu.u[3] = pk2(pe[8 * s2 + 6], pe[8 * s2 + 7]);
          pf[kt * 2 + s2] = pu.v;
        }
      }

      // O^T += V^T * P^T : 2 dt x 4 k16 steps (V rows are tau-permuted)
#pragma unroll
      for (int dt = 0; dt < 2; ++dt) {
        const int row = dt * 32 + r31, rx = row & 7;
        const unsigned short* vr = vb + row * 64;
#pragma unroll
        for (int s = 0; s < 4; ++s) {
          bf16x8 vf = *(const bf16x8*)(vr + ((s * 2 + g) ^ rx) * 8);
          o_acc[dt] = MFMA32(vf, pf[s], o_acc[dt], 0, 0, 0);
        }
      }
    }
  }
#undef STAGE_PERIOD

  // epilogue: lane-local denom (one q per lane), partner holds same q
  float ls = l_lane + __shfl_xor(l_lane, 32, 64);
  float inv = 1.0f / ls;
  const int b = bh >> 4, h = bh & 15;
  const int t = q0 + w * 32 + r31;
  unsigned short* ao = AO + ((size_t)b * 2048 + t) * 1024 + h * 64;
#pragma unroll
  for (int dt = 0; dt < 2; ++dt)
#pragma unroll
    for (int rq = 0; rq < 4; ++rq) {
      floatx4 ov;
      ov[0] = o_acc[dt][rq * 4 + 0]; ov[1] = o_acc[dt][rq * 4 + 1];
      ov[2] = o_acc[dt][rq * 4 + 2]; ov[3] = o_acc[dt][rq * 4 + 3];
      ov *= inv;
      *(bf16x4*)(ao + dt * 32 + rq * 8 + g * 4) =
          __builtin_convertvector(ov, bf16x4);
    }
}

// ---------------- GEMM2: out = AO @ WprojT^T + bproj, swapped -> float4 -----
__global__ __launch_bounds__(256) void gemm_proj(
    const unsigned short* __restrict__ A,
    const unsigned short* __restrict__ Bt,
    const float* __restrict__ bias,
    float* __restrict__ out) {
  const int K = 1024, N = 1024;
  const int m0 = blockIdx.y * 128, n0 = blockIdx.x * 64;
  const int tid = threadIdx.x, w = tid >> 6, l = tid & 63;
  const int l16 = l & 15, lq = l >> 4;

  __shared__ __align__(16) unsigned short As[128 * 64];
  __shared__ __align__(16) unsigned short Bs[64 * 64];

  floatx4 acc[2][4] = {};

  int sA[4], sB[2];
  unsigned ldsoA[4], ldsoB[2];
#pragma unroll
  for (int j = 0; j < 4; ++j) {
    int s = j * 256 + tid;
    int row = s >> 3, blk = (s & 7) ^ (row & 7);
    sA[j] = (m0 + row) * K + blk * 8;
    ldsoA[j] = (unsigned)(j * 256 + w * 64) * 8;
  }
#pragma unroll
  for (int j = 0; j < 2; ++j) {
    int s = j * 256 + tid;
    int row = s >> 3, blk = (s & 7) ^ (row & 7);
    sB[j] = (n0 + row) * K + blk * 8;
    ldsoB[j] = (unsigned)(j * 256 + w * 64) * 8;
  }

  for (int k0 = 0; k0 < K; k0 += 64) {
    __syncthreads();
#pragma unroll
    for (int j = 0; j < 4; ++j) GLD16(A + sA[j] + k0, As + ldsoA[j]);
#pragma unroll
    for (int j = 0; j < 2; ++j) GLD16(Bt + sB[j] + k0, Bs + ldsoB[j]);
    __syncthreads();
#pragma unroll
    for (int kk = 0; kk < 2; ++kk) {
      bf16x8 af[2], bf[4];
#pragma unroll
      for (int mi = 0; mi < 2; ++mi) {
        int row = w * 32 + mi * 16 + l16;
        int blk = (kk * 4 + lq) ^ (l16 & 7);
        af[mi] = *(const bf16x8*)(As + row * 64 + blk * 8);
      }
#pragma unroll
      for (int ni = 0; ni < 4; ++ni) {
        int row = ni * 16 + l16;
        int blk = (kk * 4 + lq) ^ (l16 & 7);
        bf[ni] = *(const bf16x8*)(Bs + row * 64 + blk * 8);
      }
#pragma unroll
      for (int ni = 0; ni < 4; ++ni)
#pragma unroll
        for (int mi = 0; mi < 2; ++mi)
          acc[mi][ni] = MFMA16(bf[ni], af[mi], acc[mi][ni], 0, 0, 0);
    }
  }

#pragma unroll
  for (int mi = 0; mi < 2; ++mi) {
    int t = m0 + w * 32 + mi * 16 + l16;
#pragma unroll
    for (int ni = 0; ni < 4; ++ni) {
      int col0 = n0 + ni * 16 + lq * 4;
      floatx4 bv = *(const floatx4*)(bias + col0);
      *(floatx4*)(out + (size_t)t * N + col0) = acc[mi][ni] + bv;
    }
  }
}

extern "C" void kernel_launch(void* const* d_in, const int* in_sizes, int n_in,
                              void* d_out, int out_size, void* d_ws,
                              size_t ws_size, hipStream_t stream) {
  const float* x     = (const float*)d_in[0];
  const float* Wqkv  = (const float*)d_in[1];
  const float* bqkv  = (const float*)d_in[2];
  const float* Wproj = (const float*)d_in[3];
  const float* bproj = (const float*)d_in[4];
  float* out = (float*)d_out;

  unsigned short* Xb     = (unsigned short*)d_ws;  // 4096x1024
  unsigned short* Wqkvt  = Xb + 4194304;           // 3072x1024 (transposed)
  unsigned short* Wprojt = Wqkvt + 3145728;        // 1024x1024 (transposed)
  unsigned short* Qb     = Wprojt + 1048576;       // 32x2048x64 (pre-scaled)
  unsigned short* Kb     = Qb + 4194304;           // 32x2048x64
  unsigned short* Vtb    = Kb + 4194304;           // 32x64x2048 (tau-perm t)
  unsigned short* AOb    = Vtb + 4194304;          // 4096x1024

  prologue_kernel<<<5120, 256, 0, stream>>>(x, Xb, Wqkv, Wqkvt, Wproj, Wprojt);
  gemm_qkv<<<dim3(24, 32), 256, 0, stream>>>(Xb, Wqkvt, bqkv, Qb, Kb, Vtb);
  attn_kernel<<<dim3(16, 32), 256, 0, stream>>>(Qb, Kb, Vtb, AOb);
  gemm_proj<<<dim3(16, 32), 256, 0, stream>>>(AOb, Wprojt, bproj, out);
}

// Round 5
// 164.899 us; speedup vs baseline: 1.1567x; 1.1187x over previous
//
#include <hip/hip_runtime.h>

typedef float floatx4 __attribute__((ext_vector_type(4)));
typedef float floatx16 __attribute__((ext_vector_type(16)));
typedef __bf16 bf16x8 __attribute__((ext_vector_type(8)));
typedef __bf16 bf16x4 __attribute__((ext_vector_type(4)));
typedef __bf16 bf16x2 __attribute__((ext_vector_type(2)));
typedef float floatx2 __attribute__((ext_vector_type(2)));

#define MFMA16 __builtin_amdgcn_mfma_f32_16x16x32_bf16
#define MFMA32 __builtin_amdgcn_mfma_f32_32x32x16_bf16

typedef const __attribute__((address_space(1))) void* gas_t;
typedef __attribute__((address_space(3))) void* las_t;
#define GLD16(g, l) __builtin_amdgcn_global_load_lds((gas_t)(g), (las_t)(l), 16, 0, 0)

static __device__ __forceinline__ unsigned short f2bf(float f) {
  union { float f; unsigned int u; } v; v.f = f;
  unsigned int r = v.u + 0x7fffu + ((v.u >> 16) & 1u);
  return (unsigned short)(r >> 16);
}

// pack two f32 -> one dword of 2 bf16 (RNE; compiler emits v_cvt_pk_bf16_f32)
static __device__ __forceinline__ unsigned pk2(float a, float b) {
  floatx2 v; v[0] = a; v[1] = b;
  union { bf16x2 h; unsigned u; } u;
  u.h = __builtin_convertvector(v, bf16x2);
  return u.u;
}

// ---------------- fused prologue: cast x + transpose Wqkv + transpose Wproj -
static __device__ __forceinline__ void cast_transpose_tile(
    const float* __restrict__ in, unsigned short* __restrict__ out,
    int R, int C, int bx, int by) {
  const int r0 = by * 64, c0 = bx * 64;
  const int tid = threadIdx.x;
  __shared__ float tl[64][65];
  const int rr = tid >> 4, cc = (tid & 15) * 4;
#pragma unroll
  for (int i = 0; i < 4; ++i) {
    int row = rr + i * 16;
    float4 v = *(const float4*)(in + (size_t)(r0 + row) * C + c0 + cc);
    tl[row][cc] = v.x; tl[row][cc + 1] = v.y;
    tl[row][cc + 2] = v.z; tl[row][cc + 3] = v.w;
  }
  __syncthreads();
  const int cl = tid >> 2, rbase = (tid & 3) * 16;
  unsigned short o[16];
#pragma unroll
  for (int j = 0; j < 16; ++j) o[j] = f2bf(tl[rbase + j][cl]);
  unsigned short* dst = out + (size_t)(c0 + cl) * R + r0 + rbase;
  *(uint4*)dst = *(uint4*)o;
  *(uint4*)(dst + 8) = *(uint4*)(o + 8);
}

__global__ __launch_bounds__(256) void prologue_kernel(
    const float* __restrict__ x, unsigned short* __restrict__ Xb,
    const float* __restrict__ Wqkv, unsigned short* __restrict__ Wqkvt,
    const float* __restrict__ Wproj, unsigned short* __restrict__ Wprojt) {
  const int bid = blockIdx.x;
  if (bid < 4096) {
    int i = bid * 256 + threadIdx.x;
    float4 v = ((const float4*)x)[i];
    ushort4 o;
    o.x = f2bf(v.x); o.y = f2bf(v.y); o.z = f2bf(v.z); o.w = f2bf(v.w);
    ((ushort4*)Xb)[i] = o;
  } else if (bid < 4096 + 768) {
    int b2 = bid - 4096;
    cast_transpose_tile(Wqkv, Wqkvt, 1024, 3072, b2 % 48, b2 / 48);
  } else {
    int b3 = bid - 4096 - 768;
    cast_transpose_tile(Wproj, Wprojt, 1024, 1024, b3 % 16, b3 / 16);
  }
}

// ---------------- GEMM1: QKV = Xb @ WqkvT^T + bqkv, scatter -----------------
// Q[bh][t][d] (0.5*log2e folded), Kc[bh][t][d], Vt[bh][d][t'].
// V's t-axis is stored PERMUTED by tau = within-16 involution
//   tau: {0-3}->{0-3}, {4-7}->{8-11}, {8-11}->{4-7}, {12-15}->{12-15}
// so attention's PV MFMA can consume P fragments in native S^T register
// order (positional pairing; see attn_kernel).
// K-loop is double-buffered (64 KB LDS): GLDs for tile k+1 issue right after
// the barrier, compute runs on tile k -> one full compute period of latency
// hiding (same proven pattern as attn_kernel).
__global__ __launch_bounds__(256) void gemm_qkv(
    const unsigned short* __restrict__ A,
    const unsigned short* __restrict__ Bt,
    const float* __restrict__ bias,
    unsigned short* __restrict__ Q,
    unsigned short* __restrict__ Kc,
    unsigned short* __restrict__ Vt) {
  const int K = 1024;
  const int m0 = blockIdx.y * 128, n0 = blockIdx.x * 128;
  const int tid = threadIdx.x, w = tid >> 6, l = tid & 63;
  const int l16 = l & 15, lq = l >> 4;
  const int wm = w >> 1, wn = w & 1;
  const int which = n0 >> 10;

  __shared__ __align__(16) unsigned short SH[32768];  // 2 x (As 8192 + Bs 8192)

  floatx4 acc[4][4] = {};

  int sA[4], sB[4];
  unsigned ldso[4];
#pragma unroll
  for (int j = 0; j < 4; ++j) {
    int s = j * 256 + tid;
    int row = s >> 3, blk = (s & 7) ^ (row & 7);
    sA[j] = (m0 + row) * K + blk * 8;
    sB[j] = (n0 + row) * K + blk * 8;
    ldso[j] = (unsigned)(j * 256 + w * 64) * 8;
  }

  // prologue stage: tile 0 -> buffer 0
#pragma unroll
  for (int j = 0; j < 4; ++j) {
    GLD16(A + sA[j], SH + ldso[j]);
    GLD16(Bt + sB[j], SH + 8192 + ldso[j]);
  }

  if (which == 2) {
    for (int k0 = 0; k0 < K; k0 += 64) {
      __syncthreads();  // drains the GLDs for this tile (issued last iter)
      const int cur = (k0 >> 6) & 1;
      if (k0 + 64 < K) {
        const int nxt = cur ^ 1;
#pragma unroll
        for (int j = 0; j < 4; ++j) {
          GLD16(A + sA[j] + k0 + 64, SH + nxt * 16384 + ldso[j]);
          GLD16(Bt + sB[j] + k0 + 64, SH + nxt * 16384 + 8192 + ldso[j]);
        }
      }
      const unsigned short* As = SH + cur * 16384;
      const unsigned short* Bs = SH + cur * 16384 + 8192;
#pragma unroll
      for (int kk = 0; kk < 2; ++kk) {
        bf16x8 af[4], bf[4];
#pragma unroll
        for (int mi = 0; mi < 4; ++mi) {
          int row = wm * 64 + mi * 16 + l16;
          int blk = (kk * 4 + lq) ^ (l16 & 7);
          af[mi] = *(const bf16x8*)(As + row * 64 + blk * 8);
        }
#pragma unroll
        for (int ni = 0; ni < 4; ++ni) {
          int row = wn * 64 + ni * 16 + l16;
          int blk = (kk * 4 + lq) ^ (l16 & 7);
          bf[ni] = *(const bf16x8*)(Bs + row * 64 + blk * 8);
        }
#pragma unroll
        for (int ni = 0; ni < 4; ++ni)
#pragma unroll
          for (int mi = 0; mi < 4; ++mi)
            acc[mi][ni] = MFMA16(af[mi], bf[ni], acc[mi][ni], 0, 0, 0);
      }
    }
    // V: D[t(packed)][col]; bounce to [d][t] LDS; store with tau-permuted t.
    // Global position block 8m (m=l&7) holds t = {bc..bc+3, bc+8..bc+11},
    // bc = 16*(m>>1) + 4*(m&1)  ->  two b64 LDS reads, one b128 store.
    float bv[4];
#pragma unroll
    for (int ni = 0; ni < 4; ++ni) bv[ni] = bias[n0 + wn * 64 + ni * 16 + l16];
    __syncthreads();
    unsigned short* E = SH + w * 2304;  // 32 rows x stride 72 (144B, 16B-mult)
    const int bh = (m0 >> 11) * 16 + ((n0 & 1023) >> 6) + wn;
    const int tt0 = (m0 & 2047) + wm * 64;
    const int m8 = l & 7, bc = 16 * (m8 >> 1) + 4 * (m8 & 1);
#pragma unroll
    for (int p = 0; p < 2; ++p) {
#pragma unroll
      for (int n2 = 0; n2 < 2; ++n2) {
        int ni = p * 2 + n2;
#pragma unroll
        for (int mi = 0; mi < 4; ++mi) {
          floatx4 vv = acc[mi][ni] + bv[ni];
          *(bf16x4*)(E + (n2 * 16 + l16) * 72 + mi * 16 + lq * 4) =
              __builtin_convertvector(vv, bf16x4);
        }
      }
#pragma unroll
      for (int s = 0; s < 4; ++s) {
        int dl = s * 8 + (l >> 3);
        union { bf16x4 h[2]; bf16x8 v; } uu;
        uu.h[0] = *(const bf16x4*)(E + dl * 72 + bc);
        uu.h[1] = *(const bf16x4*)(E + dl * 72 + bc + 8);
        *(bf16x8*)(Vt + ((size_t)bh * 64 + p * 32 + dl) * 2048 + tt0 +
                   m8 * 8) = uu.v;
      }
    }
  } else {
    for (int k0 = 0; k0 < K; k0 += 64) {
      __syncthreads();
      const int cur = (k0 >> 6) & 1;
      if (k0 + 64 < K) {
        const int nxt = cur ^ 1;
#pragma unroll
        for (int j = 0; j < 4; ++j) {
          GLD16(A + sA[j] + k0 + 64, SH + nxt * 16384 + ldso[j]);
          GLD16(Bt + sB[j] + k0 + 64, SH + nxt * 16384 + 8192 + ldso[j]);
        }
      }
      const unsigned short* As = SH + cur * 16384;
      const unsigned short* Bs = SH + cur * 16384 + 8192;
#pragma unroll
      for (int kk = 0; kk < 2; ++kk) {
        bf16x8 af[4], bf[4];
#pragma unroll
        for (int mi = 0; mi < 4; ++mi) {
          int row = wm * 64 + mi * 16 + l16;
          int blk = (kk * 4 + lq) ^ (l16 & 7);
          af[mi] = *(const bf16x8*)(As + row * 64 + blk * 8);
        }
#pragma unroll
        for (int ni = 0; ni < 4; ++ni) {
          int row = wn * 64 + ni * 16 + l16;
          int blk = (kk * 4 + lq) ^ (l16 & 7);
          bf[ni] = *(const bf16x8*)(Bs + row * 64 + blk * 8);
        }
#pragma unroll
        for (int ni = 0; ni < 4; ++ni)
#pragma unroll
          for (int mi = 0; mi < 4; ++mi)
            acc[mi][ni] = MFMA16(bf[ni], af[mi], acc[mi][ni], 0, 0, 0);
      }
    }
    // Q/K: D[col(packed d)][t]; bounce to [t][d] LDS, coalesced 1KB stores
    const float sc = (which == 0) ? 0.7213475204444817f : 1.0f;
    unsigned short* dst = (which == 0) ? Q : Kc;
    __syncthreads();
    unsigned short* E = SH + w * 2304;
    const int bh = (m0 >> 11) * 16 + ((n0 & 1023) >> 6) + wn;
    const size_t gbase = ((size_t)bh * 2048 + (m0 & 2047) + wm * 64) * 64;
#pragma unroll
    for (int p = 0; p < 2; ++p) {
#pragma unroll
      for (int m2 = 0; m2 < 2; ++m2) {
        int mi = p * 2 + m2;
#pragma unroll
        for (int ni = 0; ni < 4; ++ni) {
          int col0 = n0 + wn * 64 + ni * 16 + lq * 4;
          floatx4 bv = *(const floatx4*)(bias + col0);
          floatx4 vv = (acc[mi][ni] + bv) * sc;
          *(bf16x4*)(E + (m2 * 16 + l16) * 72 + ni * 16 + lq * 4) =
              __builtin_convertvector(vv, bf16x4);
        }
      }
#pragma unroll
      for (int s = 0; s < 4; ++s) {
        int rl = s * 8 + (l >> 3);
        bf16x8 vv = *(const bf16x8*)(E + rl * 72 + (l & 7) * 8);
        *(bf16x8*)(dst + gbase + (size_t)(p * 32 + rl) * 64 + (l & 7) * 8) =
            vv;
      }
    }
  }
}

// ---------------- attention: 32x32 MFMA, reg-resident P, 128k periods ------
// 4 waves x 32 q-rows, full T sweep. K/V staged in 128-k periods (2 chunks),
// double-buffered (64 KB LDS) -> GLDs get a full period (~2x compute) before
// the barrier that drains them; barriers halved to 16.
// S^T C-frag (32x32): lane = col q (l&31), rows k = (r&3)+8(r>>2)+4(l>>5).
// V's k-axis is tau-permuted in global memory (see gemm_qkv), so PV consumes
// P in NATIVE register order: pf dwords = pk2 of consecutive S regs. No
// cross-lane exchange at all.
__global__ __launch_bounds__(256, 2) void attn_kernel(
    const unsigned short* __restrict__ Q,
    const unsigned short* __restrict__ Kc,
    const unsigned short* __restrict__ Vt,
    unsigned short* __restrict__ AO) {
  const int T = 2048;
  const int bh = blockIdx.y, q0 = blockIdx.x * 128;
  const int tid = threadIdx.x, w = tid >> 6, l = tid & 63;
  const int r31 = l & 31, g = l >> 5;

  __shared__ __align__(16) unsigned short KVs[2][2][2][4096];  // 64 KB
  // [buf][K=0/V=1][chunk-in-period][64x64]

  // Q B-frags (scale+log2e pre-folded): col q = r31, k(d) = 16*ds + g*8 + j
  bf16x8 qf[4];
  {
    const unsigned short* qr =
        Q + ((size_t)bh * T + q0 + w * 32 + r31) * 64 + g * 8;
#pragma unroll
    for (int ds = 0; ds < 4; ++ds) qf[ds] = *(const bf16x8*)(qr + ds * 16);
  }

  floatx16 o_acc[2] = {};
  float l_lane = 0.f;

  const unsigned short* kbase = Kc + (size_t)bh * T * 64;
  const unsigned short* vbase = Vt + (size_t)bh * 64 * T;
  int kro[2], vro[2];
  unsigned ldso[2];
#pragma unroll
  for (int j = 0; j < 2; ++j) {
    int s = j * 256 + tid;
    int row = s >> 3, blk = (s & 7) ^ (row & 7);
    kro[j] = row * 64 + blk * 8;  // + chunk*4096
    vro[j] = row * T + blk * 8;   // + chunk*64
    ldso[j] = (unsigned)(j * 256 + (tid & 192)) * 8;  // wave-uniform base
  }

  // stage period pp (chunks 2pp, 2pp+1) into buffer nb
#define STAGE_PERIOD(pp, nb)                                              \
  {                                                                       \
    _Pragma("unroll") for (int c2 = 0; c2 < 2; ++c2) {                    \
      const int c = (pp) * 2 + c2;                                        \
      _Pragma("unroll") for (int j = 0; j < 2; ++j) {                     \
        GLD16(kbase + c * 4096 + kro[j], &KVs[nb][0][c2][ldso[j]]);       \
        GLD16(vbase + c * 64 + vro[j], &KVs[nb][1][c2][ldso[j]]);         \
      }                                                                   \
    }                                                                     \
  }

  STAGE_PERIOD(0, 0);

  for (int p = 0; p < 16; ++p) {
    __syncthreads();  // drains this wave's GLDs for period p (issued 1 ago)
    if (p < 15) {
      const int nb = (p + 1) & 1;
      STAGE_PERIOD(p + 1, nb);
    }
    const int pb = p & 1;
#pragma unroll
    for (int c2 = 0; c2 < 2; ++c2) {
      const unsigned short* kb = &KVs[pb][0][c2][0];
      const unsigned short* vb = &KVs[pb][1][c2][0];

      // QK^T: two 32k x 32q tiles
      bf16x8 pf[4];
#pragma unroll
      for (int kt = 0; kt < 2; ++kt) {
        const int row = kt * 32 + r31, rx = row & 7;
        const unsigned short* kr = kb + row * 64;
        floatx16 z = {};
#pragma unroll
        for (int ds = 0; ds < 4; ++ds)
          z = MFMA32(*(const bf16x8*)(kr + ((ds * 2 + g) ^ rx) * 8), qf[ds],
                     z, 0, 0, 0);

        float pe[16];
#pragma unroll
        for (int r = 0; r < 16; ++r) pe[r] = __builtin_amdgcn_exp2f(z[r]);
        l_lane += (((pe[0] + pe[1]) + (pe[2] + pe[3])) +
                   ((pe[4] + pe[5]) + (pe[6] + pe[7]))) +
                  (((pe[8] + pe[9]) + (pe[10] + pe[11])) +
                   ((pe[12] + pe[13]) + (pe[14] + pe[15])));
        // native-order P fragments (tau-permuted V absorbs the layout)
#pragma unroll
        for (int s2 = 0; s2 < 2; ++s2) {
          union { unsigned u[4]; bf16x8 v; } pu;
          pu.u[0] = pk2(pe[8 * s2 + 0], pe[8 * s2 + 1]);
          pu.u[1] = pk2(pe[8 * s2 + 2], pe[8 * s2 + 3]);
          pu.u[2] = pk2(pe[8 * s2 + 4], pe[8 * s2 + 5]);
          pu.u[3] = pk2(pe[8 * s2 + 6], pe[8 * s2 + 7]);
          pf[kt * 2 + s2] = pu.v;
        }
      }

      // O^T += V^T * P^T : 2 dt x 4 k16 steps (V rows are tau-permuted)
#pragma unroll
      for (int dt = 0; dt < 2; ++dt) {
        const int row = dt * 32 + r31, rx = row & 7;
        const unsigned short* vr = vb + row * 64;
#pragma unroll
        for (int s = 0; s < 4; ++s) {
          bf16x8 vf = *(const bf16x8*)(vr + ((s * 2 + g) ^ rx) * 8);
          o_acc[dt] = MFMA32(vf, pf[s], o_acc[dt], 0, 0, 0);
        }
      }
    }
  }
#undef STAGE_PERIOD

  // epilogue: lane-local denom (one q per lane), partner holds same q
  float ls = l_lane + __shfl_xor(l_lane, 32, 64);
  float inv = 1.0f / ls;
  const int b = bh >> 4, h = bh & 15;
  const int t = q0 + w * 32 + r31;
  unsigned short* ao = AO + ((size_t)b * 2048 + t) * 1024 + h * 64;
#pragma unroll
  for (int dt = 0; dt < 2; ++dt)
#pragma unroll
    for (int rq = 0; rq < 4; ++rq) {
      floatx4 ov;
      ov[0] = o_acc[dt][rq * 4 + 0]; ov[1] = o_acc[dt][rq * 4 + 1];
      ov[2] = o_acc[dt][rq * 4 + 2]; ov[3] = o_acc[dt][rq * 4 + 3];
      ov *= inv;
      *(bf16x4*)(ao + dt * 32 + rq * 8 + g * 4) =
          __builtin_convertvector(ov, bf16x4);
    }
}

// ---------------- GEMM2: out = AO @ WprojT^T + bproj, swapped -> float4 -----
// Same double-buffered prefetch structure as gemm_qkv (48 KB LDS).
__global__ __launch_bounds__(256) void gemm_proj(
    const unsigned short* __restrict__ A,
    const unsigned short* __restrict__ Bt,
    const float* __restrict__ bias,
    float* __restrict__ out) {
  const int K = 1024, N = 1024;
  const int m0 = blockIdx.y * 128, n0 = blockIdx.x * 64;
  const int tid = threadIdx.x, w = tid >> 6, l = tid & 63;
  const int l16 = l & 15, lq = l >> 4;

  __shared__ __align__(16) unsigned short SH[24576];  // 2 x (As 8192 + Bs 4096)

  floatx4 acc[2][4] = {};

  int sA[4], sB[2];
  unsigned ldsoA[4], ldsoB[2];
#pragma unroll
  for (int j = 0; j < 4; ++j) {
    int s = j * 256 + tid;
    int row = s >> 3, blk = (s & 7) ^ (row & 7);
    sA[j] = (m0 + row) * K + blk * 8;
    ldsoA[j] = (unsigned)(j * 256 + w * 64) * 8;
  }
#pragma unroll
  for (int j = 0; j < 2; ++j) {
    int s = j * 256 + tid;
    int row = s >> 3, blk = (s & 7) ^ (row & 7);
    sB[j] = (n0 + row) * K + blk * 8;
    ldsoB[j] = (unsigned)(j * 256 + w * 64) * 8;
  }

  // prologue stage: tile 0 -> buffer 0
#pragma unroll
  for (int j = 0; j < 4; ++j) GLD16(A + sA[j], SH + ldsoA[j]);
#pragma unroll
  for (int j = 0; j < 2; ++j) GLD16(Bt + sB[j], SH + 8192 + ldsoB[j]);

  for (int k0 = 0; k0 < K; k0 += 64) {
    __syncthreads();
    const int cur = (k0 >> 6) & 1;
    if (k0 + 64 < K) {
      const int nxt = cur ^ 1;
#pragma unroll
      for (int j = 0; j < 4; ++j)
        GLD16(A + sA[j] + k0 + 64, SH + nxt * 12288 + ldsoA[j]);
#pragma unroll
      for (int j = 0; j < 2; ++j)
        GLD16(Bt + sB[j] + k0 + 64, SH + nxt * 12288 + 8192 + ldsoB[j]);
    }
    const unsigned short* As = SH + cur * 12288;
    const unsigned short* Bs = SH + cur * 12288 + 8192;
#pragma unroll
    for (int kk = 0; kk < 2; ++kk) {
      bf16x8 af[2], bf[4];
#pragma unroll
      for (int mi = 0; mi < 2; ++mi) {
        int row = w * 32 + mi * 16 + l16;
        int blk = (kk * 4 + lq) ^ (l16 & 7);
        af[mi] = *(const bf16x8*)(As + row * 64 + blk * 8);
      }
#pragma unroll
      for (int ni = 0; ni < 4; ++ni) {
        int row = ni * 16 + l16;
        int blk = (kk * 4 + lq) ^ (l16 & 7);
        bf[ni] = *(const bf16x8*)(Bs + row * 64 + blk * 8);
      }
#pragma unroll
      for (int ni = 0; ni < 4; ++ni)
#pragma unroll
        for (int mi = 0; mi < 2; ++mi)
          acc[mi][ni] = MFMA16(bf[ni], af[mi], acc[mi][ni], 0, 0, 0);
    }
  }

#pragma unroll
  for (int mi = 0; mi < 2; ++mi) {
    int t = m0 + w * 32 + mi * 16 + l16;
#pragma unroll
    for (int ni = 0; ni < 4; ++ni) {
      int col0 = n0 + ni * 16 + lq * 4;
      floatx4 bv = *(const floatx4*)(bias + col0);
      *(floatx4*)(out + (size_t)t * N + col0) = acc[mi][ni] + bv;
    }
  }
}

extern "C" void kernel_launch(void* const* d_in, const int* in_sizes, int n_in,
                              void* d_out, int out_size, void* d_ws,
                              size_t ws_size, hipStream_t stream) {
  const float* x     = (const float*)d_in[0];
  const float* Wqkv  = (const float*)d_in[1];
  const float* bqkv  = (const float*)d_in[2];
  const float* Wproj = (const float*)d_in[3];
  const float* bproj = (const float*)d_in[4];
  float* out = (float*)d_out;

  unsigned short* Xb     = (unsigned short*)d_ws;  // 4096x1024
  unsigned short* Wqkvt  = Xb + 4194304;           // 3072x1024 (transposed)
  unsigned short* Wprojt = Wqkvt + 3145728;        // 1024x1024 (transposed)
  unsigned short* Qb     = Wprojt + 1048576;       // 32x2048x64 (pre-scaled)
  unsigned short* Kb     = Qb + 4194304;           // 32x2048x64
  unsigned short* Vtb    = Kb + 4194304;           // 32x64x2048 (tau-perm t)
  unsigned short* AOb    = Vtb + 4194304;          // 4096x1024

  prologue_kernel<<<5120, 256, 0, stream>>>(x, Xb, Wqkv, Wqkvt, Wproj, Wprojt);
  gemm_qkv<<<dim3(24, 32), 256, 0, stream>>>(Xb, Wqkvt, bqkv, Qb, Kb, Vtb);
  attn_kernel<<<dim3(16, 32), 256, 0, stream>>>(Qb, Kb, Vtb, AOb);
  gemm_proj<<<dim3(16, 32), 256, 0, stream>>>(AOb, Wprojt, bproj, out);
}